// Round 4
// baseline (64338.440 us; speedup 1.0000x reference)
//
#include <hip/hip_runtime.h>

// LSTMRecursiveModel: B=16, L=96, H=256, NL=2, O=32. 3168 sequential steps.
// Cooperative persistent kernel, 1 grid barrier/step, software-pipelined:
// phase p computes L0(step p) || L1(step p-1).
//
// Round 4: weights STATIONARY IN VGPRS (128/lane incl 4x batch-group dup) --
// zero per-phase LDS (round 3 died on 2048 ds_read x 12cy = 10us/phase/CU).
// All cross-WG data (h0/h1/pred) moves via agent-scope relaxed atomics
// (cache-bypassing, coherent at IF$) -- NO threadfence/release fences, which
// were causing dirty-L2 writeback thrash (WRITE_SIZE 331KB/phase for 16KB h).
// Grid: 48 WGs x 512 (16 L0 + 32 L1), 8 waves/CU, flag barrier.
//
// Per wave: owns 8 gate-rows. L0 wave wi: cols {2wi, 2wi+1} x 4 gates, k=256.
// L1 wave wi: col wi x 4 gates, concat k=512 ([h0'(s); h1(s-1)]).
// Lane = (g = lane&3: 4 batches each, kl = lane>>2: k-slice). 512 FMA/lane,
// 4-step shfl_xor k-reduce, activation + double cell state on kl==0 lanes.

#define NWG 48
#define NL0WG 16
#define LASTP 3169   // pred for jp=31 fires at p=3169

__device__ __forceinline__ float sigm(float x) { return 1.0f / (1.0f + expf(-x)); }

// ---- agent-scope coherent (cache-bypassing) access helpers ----
__device__ __forceinline__ float2 ld2v(const float* p) {
  unsigned long long v = __hip_atomic_load((const unsigned long long*)p,
                                           __ATOMIC_RELAXED, __HIP_MEMORY_SCOPE_AGENT);
  union { unsigned long long u; float2 f; } c; c.u = v; return c.f;
}
__device__ __forceinline__ void st2v(float* p, float2 f) {
  union { unsigned long long u; float2 f; } c; c.f = f;
  __hip_atomic_store((unsigned long long*)p, c.u, __ATOMIC_RELAXED, __HIP_MEMORY_SCOPE_AGENT);
}
__device__ __forceinline__ float ld1v(const float* p) {
  unsigned v = __hip_atomic_load((const unsigned*)p, __ATOMIC_RELAXED, __HIP_MEMORY_SCOPE_AGENT);
  union { unsigned u; float f; } c; c.u = v; return c.f;
}
__device__ __forceinline__ void st1v(float* p, float f) {
  union { unsigned u; float f; } c; c.f = f;
  __hip_atomic_store((unsigned*)p, c.u, __ATOMIC_RELAXED, __HIP_MEMORY_SCOPE_AGENT);
}

// ws layout (floats):
//   h0buf : [2][16][256] at 0      (double-buffered by step parity)
//   h1buf : [2][16][256] at 8192
//   predbuf: [32][16]    at 16384
//   flags  : 48 uints, 64B-strided, at 17024 (..17792)
__global__ void init_kernel(float* __restrict__ out, float* __restrict__ ws) {
  int i = blockIdx.x * blockDim.x + threadIdx.x;
  if (i < 16 * 96) out[i] = 0.0f;
  for (int j = i; j < 18432; j += gridDim.x * blockDim.x) ws[j] = 0.0f;
}

extern "C" __global__ __launch_bounds__(512, 2) void lstm_coop(
    const float* __restrict__ x_enc,
    const float* __restrict__ Wih0, const float* __restrict__ Whh0,
    const float* __restrict__ bih0, const float* __restrict__ bhh0,
    const float* __restrict__ Wih1, const float* __restrict__ Whh1,
    const float* __restrict__ bih1, const float* __restrict__ bhh1,
    const float* __restrict__ fc_w, const float* __restrict__ fc_b,
    float* __restrict__ out, float* __restrict__ ws) {
  const int w = blockIdx.x;
  const int tid = threadIdx.x;
  const int wave = tid >> 6, lane = tid & 63;
  const int g = lane & 3, kl = lane >> 2;   // batch-group (4 b's), k-slice

  float* h0buf = ws;
  float* h1buf = ws + 8192;
  float* predbuf = ws + 16384;
  unsigned* flags = (unsigned*)(ws + 17024);

  const bool isL0 = (w < NL0WG);

  // ---- stationary weights -> VGPRs (once) ----
  float4 wreg[32];      // L0: [r(0..7)][j(0..3)] 16 k each; L1: [gate][j(0..7)] 32 k each
  float biasv[8], xw[8];
  int c0 = 0, col = 0;
  if (isL0) {
    int wi = w * 8 + wave;
    c0 = wi * 2;
#pragma unroll
    for (int r = 0; r < 8; ++r) {
      int cv = r >> 2, gate = r & 3;
      int grow = gate * 256 + c0 + cv;
      const float* src = Whh0 + grow * 256 + kl * 16;
#pragma unroll
      for (int j = 0; j < 4; ++j) wreg[r * 4 + j] = *(const float4*)(src + j * 4);
      biasv[r] = bih0[grow] + bhh0[grow];
      xw[r] = Wih0[grow];   // Wih0 is (1024,1)
    }
  } else {
    int wi = (w - NL0WG) * 8 + wave;
    col = wi;
#pragma unroll
    for (int gate = 0; gate < 4; ++gate) {
      int grow = gate * 256 + col;
      const float* src = (kl < 8) ? (Wih1 + grow * 256 + kl * 32)
                                  : (Whh1 + grow * 256 + (kl - 8) * 32);
#pragma unroll
      for (int j = 0; j < 8; ++j) wreg[gate * 8 + j] = *(const float4*)(src + j * 4);
      biasv[gate] = bih1[grow] + bhh1[grow];
      xw[gate] = 0.0f;
    }
#pragma unroll
    for (int r = 4; r < 8; ++r) { biasv[r] = 0.0f; xw[r] = 0.0f; }
  }

  double cs[8];   // L0: cs[cv*4+bb]; L1: cs[bb]. Valid on kl==0 lanes.
#pragma unroll
  for (int i = 0; i < 8; ++i) cs[i] = 0.0;

  for (int p = 0; p <= LASTP; ++p) {
    float* h0prev = h0buf + ((p + 1) & 1) * 4096;   // h0(p-1) / h0'(s=p-1)
    float* h0cur  = h0buf + (p & 1) * 4096;         // h0(p) dest
    float* h1prev = h1buf + (p & 1) * 4096;         // h1(p-2)
    float* h1cur  = h1buf + ((p + 1) & 1) * 4096;   // h1(p-1) dest

    if (isL0) {
      if (p <= 3167) {
        float acc[8][4];
#pragma unroll
        for (int r = 0; r < 8; ++r)
#pragma unroll
          for (int bb = 0; bb < 4; ++bb) acc[r][bb] = 0.0f;
#pragma unroll
        for (int bb = 0; bb < 4; ++bb) {
          int b = g * 4 + bb;
          const float* hp = h0prev + b * 256 + kl * 16;
          float2 hv[8];
#pragma unroll
          for (int j = 0; j < 8; ++j) hv[j] = ld2v(hp + j * 2);
#pragma unroll
          for (int r = 0; r < 8; ++r) {
#pragma unroll
            for (int j = 0; j < 4; ++j) {
              float4 wv = wreg[r * 4 + j];
              acc[r][bb] += wv.x * hv[2 * j].x + wv.y * hv[2 * j].y +
                            wv.z * hv[2 * j + 1].x + wv.w * hv[2 * j + 1].y;
            }
          }
        }
        // k-reduce over 16 kl-lanes (lane bits 2..5)
#pragma unroll
        for (int m = 4; m <= 32; m <<= 1)
#pragma unroll
          for (int r = 0; r < 8; ++r)
#pragma unroll
            for (int bb = 0; bb < 4; ++bb) acc[r][bb] += __shfl_xor(acc[r][bb], m);

        if (kl == 0) {
#pragma unroll
          for (int bb = 0; bb < 4; ++bb) {
            int b = g * 4 + bb;
            float xv;
            {
              int s = p;
              if (s < 96) {
                xv = x_enc[b * 96 + s];
              } else {
                int sk = s - 96;
                int k = sk / 96;
                int t = sk - k * 96;
                xv = (t < 96 - k) ? x_enc[b * 96 + k + t]
                                  : ld1v(predbuf + (t - 96 + k) * 16 + b);
              }
            }
            float hcol[2];
#pragma unroll
            for (int cv = 0; cv < 2; ++cv) {
              float gi = acc[cv * 4 + 0][bb] + xv * xw[cv * 4 + 0] + biasv[cv * 4 + 0];
              float gf = acc[cv * 4 + 1][bb] + xv * xw[cv * 4 + 1] + biasv[cv * 4 + 1];
              float gg = acc[cv * 4 + 2][bb] + xv * xw[cv * 4 + 2] + biasv[cv * 4 + 2];
              float go = acc[cv * 4 + 3][bb] + xv * xw[cv * 4 + 3] + biasv[cv * 4 + 3];
              double cn = (double)sigm(gf) * cs[cv * 4 + bb] + (double)(sigm(gi) * tanhf(gg));
              hcol[cv] = sigm(go) * tanhf((float)cn);
              cs[cv * 4 + bb] = cn;
            }
            st2v(h0cur + b * 256 + c0, make_float2(hcol[0], hcol[1]));
          }
        }
      }
      // ---- prediction: h1(191+96jp) finalized at phase p-1; read parity 1 ----
      if (w == 0 && wave == 0 && p >= 193 && ((p - 193) % 96) == 0) {
        int jp = (p - 193) / 96;
        if (jp < 32) {
          int b = lane & 15, q = lane >> 4;
          const float* hsrc = h1buf + 4096 + b * 256 + q * 64;
          const float* fw = fc_w + q * 64;
          float a = 0.0f;
#pragma unroll
          for (int j = 0; j < 32; ++j) {
            float2 hv = ld2v(hsrc + j * 2);
            a += hv.x * fw[j * 2] + hv.y * fw[j * 2 + 1];
          }
          a += __shfl_xor(a, 16);
          a += __shfl_xor(a, 32);
          if (q == 0) {
            float pv = a + fc_b[0];
            st1v(predbuf + jp * 16 + b, pv);
            out[b * 96 + jp] = pv;
          }
        }
      }
    } else {
      if (p >= 1 && p <= 3168) {
        float acc[4][4];
#pragma unroll
        for (int r = 0; r < 4; ++r)
#pragma unroll
          for (int bb = 0; bb < 4; ++bb) acc[r][bb] = 0.0f;
#pragma unroll
        for (int bb = 0; bb < 4; ++bb) {
          int b = g * 4 + bb;
          const float* hp = (kl < 8) ? (h0prev + b * 256 + kl * 32)
                                     : (h1prev + b * 256 + kl * 32 - 256);
          float2 hv[16];
#pragma unroll
          for (int j = 0; j < 16; ++j) hv[j] = ld2v(hp + j * 2);
#pragma unroll
          for (int r = 0; r < 4; ++r) {
#pragma unroll
            for (int j = 0; j < 8; ++j) {
              float4 wv = wreg[r * 8 + j];
              acc[r][bb] += wv.x * hv[2 * j].x + wv.y * hv[2 * j].y +
                            wv.z * hv[2 * j + 1].x + wv.w * hv[2 * j + 1].y;
            }
          }
        }
#pragma unroll
        for (int m = 4; m <= 32; m <<= 1)
#pragma unroll
          for (int r = 0; r < 4; ++r)
#pragma unroll
            for (int bb = 0; bb < 4; ++bb) acc[r][bb] += __shfl_xor(acc[r][bb], m);

        if (kl == 0) {
#pragma unroll
          for (int bb = 0; bb < 4; ++bb) {
            int b = g * 4 + bb;
            float gi = acc[0][bb] + biasv[0];
            float gf = acc[1][bb] + biasv[1];
            float gg = acc[2][bb] + biasv[2];
            float go = acc[3][bb] + biasv[3];
            double cn = (double)sigm(gf) * cs[bb] + (double)(sigm(gi) * tanhf(gg));
            float hn = sigm(go) * tanhf((float)cn);
            cs[bb] = cn;
            st1v(h1cur + b * 256 + col, hn);
          }
        }
      }
    }

    // ---- grid barrier: flag store + poll-all. No fences: all shared data
    // moved via agent-scope atomics; __syncthreads drains each wave's vmcnt. ----
    __syncthreads();
    if (tid == 0) {
      __hip_atomic_store(&flags[w * 16], (unsigned)(p + 1), __ATOMIC_RELAXED,
                         __HIP_MEMORY_SCOPE_AGENT);
    }
    if (wave == 0) {
      const bool active = lane < NWG;
      const unsigned* myf = flags + (active ? lane : 0) * 16;
      const unsigned tgt = (unsigned)(p + 1);
      while (!__all(!active ||
                    __hip_atomic_load(myf, __ATOMIC_RELAXED,
                                      __HIP_MEMORY_SCOPE_AGENT) >= tgt)) {
      }
    }
    __syncthreads();
  }
}

extern "C" void kernel_launch(void* const* d_in, const int* in_sizes, int n_in,
                              void* d_out, int out_size, void* d_ws, size_t ws_size,
                              hipStream_t stream) {
  const float* x_enc = (const float*)d_in[0];
  const float* Wih0 = (const float*)d_in[4];
  const float* Whh0 = (const float*)d_in[5];
  const float* bih0 = (const float*)d_in[6];
  const float* bhh0 = (const float*)d_in[7];
  const float* Wih1 = (const float*)d_in[8];
  const float* Whh1 = (const float*)d_in[9];
  const float* bih1 = (const float*)d_in[10];
  const float* bhh1 = (const float*)d_in[11];
  const float* fc_w = (const float*)d_in[12];
  const float* fc_b = (const float*)d_in[13];
  float* out = (float*)d_out;
  float* ws = (float*)d_ws;

  hipLaunchKernelGGL(init_kernel, dim3(8), dim3(256), 0, stream, out, ws);

  void* args[] = {&x_enc, &Wih0, &Whh0, &bih0, &bhh0, &Wih1, &Whh1, &bih1, &bhh1,
                  &fc_w, &fc_b, &out, &ws};
  (void)hipLaunchCooperativeKernel((void*)lstm_coop, dim3(NWG), dim3(512), args,
                                   0u, stream);
}